// Round 2
// 2682.048 us; speedup vs baseline: 1.1678x; 1.1678x over previous
//
#include <hip/hip_runtime.h>

#define B_SZ   8192
#define NUM_E  20000
#define H_DIM  512
#define C_DIM  50
#define KHW    25600   // C_DIM * H_DIM
#define EPS    1e-5f
#define KSPLIT 8       // fc_gemm split-K factor: each split covers 512/8 = 64 h values

typedef short bf16x8 __attribute__((ext_vector_type(8)));
typedef float f32x4  __attribute__((ext_vector_type(4)));

__device__ __forceinline__ float bf2f(unsigned short u) {
  return __uint_as_float(((unsigned int)u) << 16);
}
__device__ __forceinline__ unsigned short f2bf(float f) {
  unsigned int u = __float_as_uint(f);
  return (unsigned short)((u + 0x7FFFu + ((u >> 16) & 1u)) >> 16);
}

// ---------------- f32 -> bf16 bulk convert ----------------
__global__ __launch_bounds__(256) void cvt_bf16_kernel(const float* __restrict__ in,
                                                       unsigned short* __restrict__ out,
                                                       int n4) {
  int i = blockIdx.x * 256 + threadIdx.x;
  int stride = gridDim.x * 256;
  for (; i < n4; i += stride) {
    float4 v = reinterpret_cast<const float4*>(in)[i];
    ushort4 o;
    o.x = f2bf(v.x); o.y = f2bf(v.y); o.z = f2bf(v.z); o.w = f2bf(v.w);
    reinterpret_cast<ushort4*>(out)[i] = o;
  }
}

// ---------------- bn0 stats: per-channel (3) sum & sumsq over B*H ----------------
__global__ __launch_bounds__(256) void bn0_stats_kernel(const int* __restrict__ facts,
                                                        const float* __restrict__ ent,
                                                        const float* __restrict__ rel,
                                                        const float* __restrict__ bias,
                                                        float* __restrict__ stats) {
  const int tid = threadIdx.x;
  float s0=0.f,s1=0.f,s2=0.f,q0=0.f,q1=0.f,q2=0.f;
  const int stride = gridDim.x * 256;
  for (int i = blockIdx.x * 256 + tid; i < B_SZ * H_DIM; i += stride) {
    int b = i >> 9, h = i & 511;
    int f0 = facts[b * 3 + 0], f1 = facts[b * 3 + 1];
    float v0 = ent[f0 * H_DIM + h];
    float v1 = rel[f1 * H_DIM + h];
    float v2 = bias[f0 * H_DIM + h];
    s0 += v0; q0 += v0 * v0;
    s1 += v1; q1 += v1 * v1;
    s2 += v2; q2 += v2 * v2;
  }
  __shared__ float red[256];
  float vals[6] = {s0, s1, s2, q0, q1, q2};
  for (int j = 0; j < 6; ++j) {
    red[tid] = vals[j]; __syncthreads();
    for (int off = 128; off > 0; off >>= 1) {
      if (tid < off) red[tid] += red[tid + off];
      __syncthreads();
    }
    if (tid == 0) atomicAdd(&stats[j], red[0]);
    __syncthreads();
  }
}

// ---------------- xn = bn0(gathered x), stored bf16 [B][3][H] ----------------
__global__ __launch_bounds__(256) void xn_kernel(const int* __restrict__ facts,
                                                 const float* __restrict__ ent,
                                                 const float* __restrict__ rel,
                                                 const float* __restrict__ bias,
                                                 const float* __restrict__ g0,
                                                 const float* __restrict__ b0,
                                                 const float* __restrict__ stats,
                                                 unsigned short* __restrict__ xn) {
  const float invN = 1.0f / 4194304.0f;
  float a[3], c[3];
  #pragma unroll
  for (int ch = 0; ch < 3; ++ch) {
    float mean = stats[ch] * invN;
    float var  = stats[3 + ch] * invN - mean * mean;
    float sc = g0[ch] * rsqrtf(var + EPS);
    a[ch] = sc;
    c[ch] = b0[ch] - mean * sc;
  }
  const int stride = gridDim.x * 256;
  for (int i = blockIdx.x * 256 + threadIdx.x; i < B_SZ * H_DIM; i += stride) {
    int b = i >> 9, h = i & 511;
    int f0 = facts[b * 3 + 0], f1 = facts[b * 3 + 1];
    xn[(b * 3 + 0) * H_DIM + h] = f2bf(fmaf(ent[f0 * H_DIM + h],  a[0], c[0]));
    xn[(b * 3 + 1) * H_DIM + h] = f2bf(fmaf(rel[f1 * H_DIM + h],  a[1], c[1]));
    xn[(b * 3 + 2) * H_DIM + h] = f2bf(fmaf(bias[f0 * H_DIM + h], a[2], c[2]));
  }
}

// ---------------- conv output stats (pre-bn1): per-C sum & sumsq over B*H ----------------
__global__ __launch_bounds__(256) void conv_stats_kernel(const unsigned short* __restrict__ xn,
                                                         const float* __restrict__ conv_w,
                                                         const float* __restrict__ conv_b,
                                                         float* __restrict__ stats) {
  const int tid = threadIdx.x;
  const int cg = blockIdx.y;   // 7 groups of 8 channels
  float w[8][9], cb[8];
  #pragma unroll
  for (int j = 0; j < 8; ++j) {
    int c = cg * 8 + j;
    if (c < C_DIM) {
      #pragma unroll
      for (int t = 0; t < 9; ++t) w[j][t] = conv_w[c * 9 + t];
      cb[j] = conv_b[c];
    } else {
      #pragma unroll
      for (int t = 0; t < 9; ++t) w[j][t] = 0.f;
      cb[j] = 0.f;
    }
  }
  float s[8], qv[8];
  #pragma unroll
  for (int j = 0; j < 8; ++j) { s[j] = 0.f; qv[j] = 0.f; }
  const int stride = gridDim.x * 256;
  for (int i = blockIdx.x * 256 + tid; i < B_SZ * H_DIM; i += stride) {
    int b = i >> 9, h = i & 511;
    float xv[9];
    #pragma unroll
    for (int ii = 0; ii < 3; ++ii) {
      const unsigned short* row = xn + ((size_t)b * 3 + ii) * H_DIM;
      xv[ii * 3 + 0] = (h > 0)   ? bf2f(row[h - 1]) : 0.f;
      xv[ii * 3 + 1] = bf2f(row[h]);
      xv[ii * 3 + 2] = (h < 511) ? bf2f(row[h + 1]) : 0.f;
    }
    #pragma unroll
    for (int j = 0; j < 8; ++j) {
      float v = cb[j];
      #pragma unroll
      for (int t = 0; t < 9; ++t) v = fmaf(w[j][t], xv[t], v);
      s[j] += v; qv[j] += v * v;
    }
  }
  __shared__ float red[256];
  #pragma unroll 1
  for (int j = 0; j < 8; ++j) {
    int c = cg * 8 + j;
    red[tid] = s[j]; __syncthreads();
    for (int off = 128; off > 0; off >>= 1) {
      if (tid < off) red[tid] += red[tid + off];
      __syncthreads();
    }
    if (tid == 0 && c < C_DIM) atomicAdd(&stats[8 + c], red[0]);
    __syncthreads();
    red[tid] = qv[j]; __syncthreads();
    for (int off = 128; off > 0; off >>= 1) {
      if (tid < off) red[tid] += red[tid + off];
      __syncthreads();
    }
    if (tid == 0 && c < C_DIM) atomicAdd(&stats[64 + c], red[0]);
    __syncthreads();
  }
}

// ---------------- fold bn1 into conv weights: cwf[c][0..8]=w*sc, cwf[c][9]=tc ----------------
__global__ __launch_bounds__(64) void bn1_fold_kernel(const float* __restrict__ conv_w,
                                                      const float* __restrict__ conv_b,
                                                      const float* __restrict__ g1,
                                                      const float* __restrict__ b1,
                                                      const float* __restrict__ stats,
                                                      float* __restrict__ cwf) {
  const int c = threadIdx.x;
  if (c >= C_DIM) return;
  const float invN = 1.0f / 4194304.0f;
  float mean = stats[8 + c] * invN;
  float var  = stats[64 + c] * invN - mean * mean;
  float sc = g1[c] * rsqrtf(var + EPS);
  float tc = fmaf(sc, conv_b[c], b1[c] - mean * sc);
  #pragma unroll
  for (int t = 0; t < 9; ++t) cwf[c * 10 + t] = conv_w[c * 9 + t] * sc;
  cwf[c * 10 + 9] = tc;
}

// ---------------- fused conv+bn1+relu+fc GEMM (split-K): z[8192][512] partials ----------------
// Block: 256 thr = 4 waves (2x2), wave tile 64x64 (4x4 of 16x16x32), block tile 128x128.
// Grid (64 m-tiles, 4 n-tiles, KSPLIT h-splits). Each split handles 64 h values (2 k-tiles),
// accumulates its partial into z via atomicAdd (z pre-zeroed).
// NOTE: fc_b is dropped entirely — it is zeros, and a per-column constant cancels in bn2 anyway.
__global__ __launch_bounds__(256) void fc_gemm_kernel(const unsigned short* __restrict__ xn,
                                                      const unsigned short* __restrict__ fcw,
                                                      const float* __restrict__ cwf,
                                                      float* __restrict__ z) {
  const int tid  = threadIdx.x;
  const int m0   = blockIdx.x * 128;
  const int n0   = blockIdx.y * 128;
  const int hs   = blockIdx.z * 64;   // this split's h range: [hs, hs+64)
  const int lane = tid & 63;
  const int wave = tid >> 6;
  const int wm   = (wave >> 1) * 64;
  const int wn   = (wave & 1) * 64;
  const int l15  = lane & 15;
  const int qd   = lane >> 4;
  const int am   = tid >> 1;          // row 0..127 this thread generates
  const int ah   = (tid & 1) * 16;    // k-base (0 or 16) within 32-wide tile

  __shared__ unsigned short xstage[128][3][36];  // bn0-normalized window [h0-1, h0+33); i-stride padded to 36 for u32 reads
  __shared__ unsigned short albuf[2][128][40];   // A tile, k padded 32->40 (2-way banks)

  f32x4 acc[4][4];
  #pragma unroll
  for (int a = 0; a < 4; ++a)
    #pragma unroll
    for (int b = 0; b < 4; ++b) {
      f32x4 zv = {0.f, 0.f, 0.f, 0.f};
      acc[a][b] = zv;
    }

  const unsigned short* bbase[4];
  #pragma unroll
  for (int tn = 0; tn < 4; ++tn)
    bbase[tn] = fcw + (size_t)(n0 + wn + tn * 16 + l15) * KHW + qd * 8;

  float xw[3][18];

  for (int h0 = hs; h0 < hs + 64; h0 += 32) {
    __syncthreads();
    // stage xn window (coalesced-ish)
    for (int idx = tid; idx < 128 * 3 * 34; idx += 256) {
      int m = idx / 102;
      int rem = idx - m * 102;
      int i = rem / 34;
      int x = rem - i * 34;
      int h = h0 - 1 + x;
      unsigned short v = 0;
      if (h >= 0 && h < H_DIM) v = xn[((size_t)(m0 + m) * 3 + i) * H_DIM + h];
      xstage[m][i][x] = v;
    }
    __syncthreads();
    // per-thread register window (covers taps for its 16 k's) — load as u32 pairs, unpack
    #pragma unroll
    for (int i = 0; i < 3; ++i) {
      const unsigned int* p = (const unsigned int*)&xstage[am][i][ah];
      #pragma unroll
      for (int j = 0; j < 9; ++j) {
        unsigned int u = p[j];
        xw[i][2 * j]     = __uint_as_float(u << 16);
        xw[i][2 * j + 1] = __uint_as_float(u & 0xFFFF0000u);
      }
    }

    auto agen = [&](int c, int bb) {
      float w[9], tc;
      const float* cw = cwf + c * 10;
      #pragma unroll
      for (int t = 0; t < 9; ++t) w[t] = cw[t];
      tc = cw[9];
      unsigned int pk[8];
      #pragma unroll
      for (int kp = 0; kp < 8; ++kp) {
        float vv[2];
        #pragma unroll
        for (int e = 0; e < 2; ++e) {
          int kk = kp * 2 + e;
          float v = tc;
          #pragma unroll
          for (int i = 0; i < 3; ++i) {
            v = fmaf(w[i * 3 + 0], xw[i][kk],     v);
            v = fmaf(w[i * 3 + 1], xw[i][kk + 1], v);
            v = fmaf(w[i * 3 + 2], xw[i][kk + 2], v);
          }
          vv[e] = fmaxf(v, 0.f);
        }
        asm("v_cvt_pk_bf16_f32 %0, %1, %2" : "=v"(pk[kp]) : "v"(vv[0]), "v"(vv[1]));
      }
      uint4* d = (uint4*)&albuf[bb][am][ah];
      d[0] = make_uint4(pk[0], pk[1], pk[2], pk[3]);
      d[1] = make_uint4(pk[4], pk[5], pk[6], pk[7]);
    };

    agen(0, 0);
    bf16x8 bcur[4];
    #pragma unroll
    for (int tn = 0; tn < 4; ++tn)
      bcur[tn] = *(const bf16x8*)(bbase[tn] + h0);
    __syncthreads();

    #pragma unroll 1
    for (int c = 0; c < C_DIM; ++c) {
      bf16x8 af[4];
      #pragma unroll
      for (int tm = 0; tm < 4; ++tm)
        af[tm] = *(const bf16x8*)&albuf[c & 1][wm + tm * 16 + l15][qd * 8];
      #pragma unroll
      for (int tm = 0; tm < 4; ++tm)
        #pragma unroll
        for (int tn = 0; tn < 4; ++tn)
          acc[tm][tn] = __builtin_amdgcn_mfma_f32_16x16x32_bf16(af[tm], bcur[tn], acc[tm][tn], 0, 0, 0);
      if (c + 1 < C_DIM) {
        bf16x8 bnew[4];
        #pragma unroll
        for (int tn = 0; tn < 4; ++tn)
          bnew[tn] = *(const bf16x8*)(bbase[tn] + (c + 1) * H_DIM + h0);
        agen(c + 1, (c + 1) & 1);
        __syncthreads();
        #pragma unroll
        for (int tn = 0; tn < 4; ++tn) bcur[tn] = bnew[tn];
      } else {
        __syncthreads();
      }
    }
  }

  #pragma unroll
  for (int tm = 0; tm < 4; ++tm)
    #pragma unroll
    for (int tn = 0; tn < 4; ++tn) {
      int col = n0 + wn + tn * 16 + l15;
      #pragma unroll
      for (int r = 0; r < 4; ++r) {
        int row = m0 + wm + tm * 16 + qd * 4 + r;
        atomicAdd(&z[(size_t)row * H_DIM + col], acc[tm][tn][r]);
      }
    }
}

// ---------------- bn2 stats: per-column (512) sum & sumsq over B ----------------
__global__ __launch_bounds__(256) void bn2_stats_kernel(const float* __restrict__ z,
                                                        float* __restrict__ stats) {
  const int tid = threadIdx.x;
  const int col = blockIdx.y * 64 + (tid & 63);
  float s = 0.f, qq = 0.f;
  for (int r = blockIdx.x * 4 + (tid >> 6); r < B_SZ; r += gridDim.x * 4) {
    float v = z[(size_t)r * H_DIM + col];
    s += v; qq += v * v;
  }
  __shared__ float ls[256], lq[256];
  ls[tid] = s; lq[tid] = qq;
  __syncthreads();
  if (tid < 64) {
    s  = ls[tid] + ls[tid + 64] + ls[tid + 128] + ls[tid + 192];
    qq = lq[tid] + lq[tid + 64] + lq[tid + 128] + lq[tid + 192];
    atomicAdd(&stats[128 + col], s);
    atomicAdd(&stats[640 + col], qq);
  }
}

// ---------------- zr = bf16(relu(bn2(z))) ----------------
__global__ __launch_bounds__(256) void zr_kernel(const float* __restrict__ z,
                                                 const float* __restrict__ stats,
                                                 const float* __restrict__ g2,
                                                 const float* __restrict__ b2,
                                                 unsigned short* __restrict__ zrb) {
  const float invB = 1.0f / 8192.0f;
  const int stride = gridDim.x * 256;
  for (int i = blockIdx.x * 256 + threadIdx.x; i < B_SZ * H_DIM; i += stride) {
    int col = i & 511;
    float mean = stats[128 + col] * invB;
    float var  = stats[640 + col] * invB - mean * mean;
    float sc = g2[col] * rsqrtf(var + EPS);
    float tc = b2[col] - mean * sc;
    float v = fmaf(z[i], sc, tc);
    zrb[i] = f2bf(fmaxf(v, 0.f));
  }
}

// ---------------- score GEMM: out[8192][20000] = zr @ ent^T ----------------
__global__ __launch_bounds__(256) void score_gemm_kernel(const unsigned short* __restrict__ zrb,
                                                         const unsigned short* __restrict__ entb,
                                                         float* __restrict__ out) {
  const int tid  = threadIdx.x;
  const int m0   = blockIdx.x * 128;
  const int n0   = blockIdx.y * 128;
  const int lane = tid & 63;
  const int wave = tid >> 6;
  const int wm   = (wave >> 1) * 64;
  const int wn   = (wave & 1) * 64;
  const int l15  = lane & 15;
  const int qd   = lane >> 4;

  f32x4 acc[4][4];
  #pragma unroll
  for (int a = 0; a < 4; ++a)
    #pragma unroll
    for (int b = 0; b < 4; ++b) {
      f32x4 zv = {0.f, 0.f, 0.f, 0.f};
      acc[a][b] = zv;
    }

  const unsigned short* ap[4];
  const unsigned short* bp[4];
  #pragma unroll
  for (int t = 0; t < 4; ++t) {
    ap[t] = zrb + (size_t)(m0 + wm + t * 16 + l15) * H_DIM + qd * 8;
    int e = n0 + wn + t * 16 + l15;
    if (e >= NUM_E) e = NUM_E - 1;
    bp[t] = entb + (size_t)e * H_DIM + qd * 8;
  }
  #pragma unroll 2
  for (int k0 = 0; k0 < H_DIM; k0 += 32) {
    bf16x8 af[4], bf[4];
    #pragma unroll
    for (int t = 0; t < 4; ++t) {
      af[t] = *(const bf16x8*)(ap[t] + k0);
      bf[t] = *(const bf16x8*)(bp[t] + k0);
    }
    #pragma unroll
    for (int tm = 0; tm < 4; ++tm)
      #pragma unroll
      for (int tn = 0; tn < 4; ++tn)
        acc[tm][tn] = __builtin_amdgcn_mfma_f32_16x16x32_bf16(af[tm], bf[tn], acc[tm][tn], 0, 0, 0);
  }
  #pragma unroll
  for (int tm = 0; tm < 4; ++tm)
    #pragma unroll
    for (int tn = 0; tn < 4; ++tn) {
      int col = n0 + wn + tn * 16 + l15;
      if (col < NUM_E) {
        #pragma unroll
        for (int r = 0; r < 4; ++r) {
          int row = m0 + wm + tm * 16 + qd * 4 + r;
          out[(size_t)row * NUM_E + col] = acc[tm][tn][r];
        }
      }
    }
}

// ---------------- in-place log_softmax over rows of 20000 ----------------
__global__ __launch_bounds__(256) void logsoftmax_kernel(float* __restrict__ out) {
  const int b = blockIdx.x;
  float* row = out + (size_t)b * NUM_E;
  const int tid = threadIdx.x;
  float m = -3.0e38f, s = 0.f;
  for (int c = tid; c < NUM_E; c += 256) {
    float x = row[c];
    if (x > m) { s = s * __expf(m - x) + 1.f; m = x; }
    else       { s += __expf(x - m); }
  }
  __shared__ float lm[256], ls[256];
  lm[tid] = m; ls[tid] = s;
  __syncthreads();
  for (int off = 128; off > 0; off >>= 1) {
    if (tid < off) {
      float m2 = lm[tid + off], s2 = ls[tid + off];
      float m1 = lm[tid],       s1 = ls[tid];
      float M = fmaxf(m1, m2);
      ls[tid] = s1 * __expf(m1 - M) + s2 * __expf(m2 - M);
      lm[tid] = M;
    }
    __syncthreads();
  }
  const float lse = lm[0] + __logf(ls[0]);
  for (int c = tid; c < NUM_E; c += 256) row[c] -= lse;
}

extern "C" void kernel_launch(void* const* d_in, const int* in_sizes, int n_in,
                              void* d_out, int out_size, void* d_ws, size_t ws_size,
                              hipStream_t stream) {
  const int*   facts  = (const int*)d_in[0];
  const float* ent    = (const float*)d_in[1];
  const float* rel    = (const float*)d_in[2];
  const float* erb    = (const float*)d_in[3];
  const float* conv_w = (const float*)d_in[4];
  const float* conv_b = (const float*)d_in[5];
  const float* fc_w   = (const float*)d_in[6];
  // d_in[7] = fc_b: unused — zeros, and a per-column bias cancels exactly in bn2.
  const float* g0     = (const float*)d_in[8];
  const float* b0     = (const float*)d_in[9];
  const float* g1     = (const float*)d_in[10];
  const float* b1     = (const float*)d_in[11];
  const float* g2     = (const float*)d_in[12];
  const float* b2     = (const float*)d_in[13];

  char* ws = (char*)d_ws;
  // ws layout (total ~92.6 MB):
  float*          stats = (float*)ws;                          // 16384 B (zeroed); cwf at +8192
  float*          cwf   = (float*)(ws + 8192);                 // 2000 B (50 x 10 folded conv/bn1)
  unsigned short* xn    = (unsigned short*)(ws + 16384);       // 25,165,824 B
  unsigned short* fcw   = (unsigned short*)(ws + 25182208);    // 26,214,400 B
  unsigned short* entb  = (unsigned short*)(ws + 51396608);    // 20,480,000 B
  float*          z     = (float*)(ws + 71876608);             // 16,777,216 B (zeroed; split-K atomics)
  unsigned short* zrb   = (unsigned short*)(ws + 88653824);    //  8,388,608 B
  float* out = (float*)d_out;

  hipMemsetAsync(stats, 0, 16384, stream);
  hipMemsetAsync(z, 0, 16777216, stream);
  cvt_bf16_kernel<<<2048, 256, 0, stream>>>(ent, entb, (NUM_E * H_DIM) / 4);
  cvt_bf16_kernel<<<2048, 256, 0, stream>>>(fc_w, fcw, (H_DIM * KHW) / 4);
  bn0_stats_kernel<<<1024, 256, 0, stream>>>(facts, ent, rel, erb, stats);
  xn_kernel<<<1024, 256, 0, stream>>>(facts, ent, rel, erb, g0, b0, stats, xn);
  conv_stats_kernel<<<dim3(512, 7), 256, 0, stream>>>(xn, conv_w, conv_b, stats);
  bn1_fold_kernel<<<1, 64, 0, stream>>>(conv_w, conv_b, g1, b1, stats, cwf);
  fc_gemm_kernel<<<dim3(64, 4, KSPLIT), 256, 0, stream>>>(xn, fcw, cwf, z);
  bn2_stats_kernel<<<dim3(64, 8), 256, 0, stream>>>(z, stats);
  zr_kernel<<<2048, 256, 0, stream>>>(z, stats, g2, b2, zrb);
  score_gemm_kernel<<<dim3(64, 157), 256, 0, stream>>>(zrb, entb, out);
  logsoftmax_kernel<<<8192, 256, 0, stream>>>(out);
}

// Round 3
// 2526.354 us; speedup vs baseline: 1.2398x; 1.0616x over previous
//
#include <hip/hip_runtime.h>

#define B_SZ   8192
#define NUM_E  20000
#define H_DIM  512
#define C_DIM  50
#define KHW    25600   // C_DIM * H_DIM
#define EPS    1e-5f
#define KSPLIT 8       // fc_gemm split-K factor: each split covers 512/8 = 64 h values
#define NBLK   157     // score n-blocks (157*128 >= 20000)

typedef short bf16x8 __attribute__((ext_vector_type(8)));
typedef float f32x4  __attribute__((ext_vector_type(4)));

__device__ __forceinline__ float bf2f(unsigned short u) {
  return __uint_as_float(((unsigned int)u) << 16);
}
__device__ __forceinline__ unsigned short f2bf(float f) {
  unsigned int u = __float_as_uint(f);
  return (unsigned short)((u + 0x7FFFu + ((u >> 16) & 1u)) >> 16);
}

// ---------------- f32 -> bf16 bulk convert ----------------
__global__ __launch_bounds__(256) void cvt_bf16_kernel(const float* __restrict__ in,
                                                       unsigned short* __restrict__ out,
                                                       int n4) {
  int i = blockIdx.x * 256 + threadIdx.x;
  int stride = gridDim.x * 256;
  for (; i < n4; i += stride) {
    float4 v = reinterpret_cast<const float4*>(in)[i];
    ushort4 o;
    o.x = f2bf(v.x); o.y = f2bf(v.y); o.z = f2bf(v.z); o.w = f2bf(v.w);
    reinterpret_cast<ushort4*>(out)[i] = o;
  }
}

// ---------------- bn0 stats: per-channel (3) sum & sumsq over B*H ----------------
__global__ __launch_bounds__(256) void bn0_stats_kernel(const int* __restrict__ facts,
                                                        const float* __restrict__ ent,
                                                        const float* __restrict__ rel,
                                                        const float* __restrict__ bias,
                                                        float* __restrict__ stats) {
  const int tid = threadIdx.x;
  float s0=0.f,s1=0.f,s2=0.f,q0=0.f,q1=0.f,q2=0.f;
  const int stride = gridDim.x * 256;
  for (int i = blockIdx.x * 256 + tid; i < B_SZ * H_DIM; i += stride) {
    int b = i >> 9, h = i & 511;
    int f0 = facts[b * 3 + 0], f1 = facts[b * 3 + 1];
    float v0 = ent[f0 * H_DIM + h];
    float v1 = rel[f1 * H_DIM + h];
    float v2 = bias[f0 * H_DIM + h];
    s0 += v0; q0 += v0 * v0;
    s1 += v1; q1 += v1 * v1;
    s2 += v2; q2 += v2 * v2;
  }
  __shared__ float red[256];
  float vals[6] = {s0, s1, s2, q0, q1, q2};
  for (int j = 0; j < 6; ++j) {
    red[tid] = vals[j]; __syncthreads();
    for (int off = 128; off > 0; off >>= 1) {
      if (tid < off) red[tid] += red[tid + off];
      __syncthreads();
    }
    if (tid == 0) atomicAdd(&stats[j], red[0]);
    __syncthreads();
  }
}

// ---------------- xn = bn0(gathered x), stored bf16 [B][3][H] ----------------
__global__ __launch_bounds__(256) void xn_kernel(const int* __restrict__ facts,
                                                 const float* __restrict__ ent,
                                                 const float* __restrict__ rel,
                                                 const float* __restrict__ bias,
                                                 const float* __restrict__ g0,
                                                 const float* __restrict__ b0,
                                                 const float* __restrict__ stats,
                                                 unsigned short* __restrict__ xn) {
  const float invN = 1.0f / 4194304.0f;
  float a[3], c[3];
  #pragma unroll
  for (int ch = 0; ch < 3; ++ch) {
    float mean = stats[ch] * invN;
    float var  = stats[3 + ch] * invN - mean * mean;
    float sc = g0[ch] * rsqrtf(var + EPS);
    a[ch] = sc;
    c[ch] = b0[ch] - mean * sc;
  }
  const int stride = gridDim.x * 256;
  for (int i = blockIdx.x * 256 + threadIdx.x; i < B_SZ * H_DIM; i += stride) {
    int b = i >> 9, h = i & 511;
    int f0 = facts[b * 3 + 0], f1 = facts[b * 3 + 1];
    xn[(b * 3 + 0) * H_DIM + h] = f2bf(fmaf(ent[f0 * H_DIM + h],  a[0], c[0]));
    xn[(b * 3 + 1) * H_DIM + h] = f2bf(fmaf(rel[f1 * H_DIM + h],  a[1], c[1]));
    xn[(b * 3 + 2) * H_DIM + h] = f2bf(fmaf(bias[f0 * H_DIM + h], a[2], c[2]));
  }
}

// ---------------- conv output stats (pre-bn1): per-C sum & sumsq over B*H ----------------
__global__ __launch_bounds__(256) void conv_stats_kernel(const unsigned short* __restrict__ xn,
                                                         const float* __restrict__ conv_w,
                                                         const float* __restrict__ conv_b,
                                                         float* __restrict__ stats) {
  const int tid = threadIdx.x;
  const int cg = blockIdx.y;   // 7 groups of 8 channels
  float w[8][9], cb[8];
  #pragma unroll
  for (int j = 0; j < 8; ++j) {
    int c = cg * 8 + j;
    if (c < C_DIM) {
      #pragma unroll
      for (int t = 0; t < 9; ++t) w[j][t] = conv_w[c * 9 + t];
      cb[j] = conv_b[c];
    } else {
      #pragma unroll
      for (int t = 0; t < 9; ++t) w[j][t] = 0.f;
      cb[j] = 0.f;
    }
  }
  float s[8], qv[8];
  #pragma unroll
  for (int j = 0; j < 8; ++j) { s[j] = 0.f; qv[j] = 0.f; }
  const int stride = gridDim.x * 256;
  for (int i = blockIdx.x * 256 + tid; i < B_SZ * H_DIM; i += stride) {
    int b = i >> 9, h = i & 511;
    float xv[9];
    #pragma unroll
    for (int ii = 0; ii < 3; ++ii) {
      const unsigned short* row = xn + ((size_t)b * 3 + ii) * H_DIM;
      xv[ii * 3 + 0] = (h > 0)   ? bf2f(row[h - 1]) : 0.f;
      xv[ii * 3 + 1] = bf2f(row[h]);
      xv[ii * 3 + 2] = (h < 511) ? bf2f(row[h + 1]) : 0.f;
    }
    #pragma unroll
    for (int j = 0; j < 8; ++j) {
      float v = cb[j];
      #pragma unroll
      for (int t = 0; t < 9; ++t) v = fmaf(w[j][t], xv[t], v);
      s[j] += v; qv[j] += v * v;
    }
  }
  __shared__ float red[256];
  #pragma unroll 1
  for (int j = 0; j < 8; ++j) {
    int c = cg * 8 + j;
    red[tid] = s[j]; __syncthreads();
    for (int off = 128; off > 0; off >>= 1) {
      if (tid < off) red[tid] += red[tid + off];
      __syncthreads();
    }
    if (tid == 0 && c < C_DIM) atomicAdd(&stats[8 + c], red[0]);
    __syncthreads();
    red[tid] = qv[j]; __syncthreads();
    for (int off = 128; off > 0; off >>= 1) {
      if (tid < off) red[tid] += red[tid + off];
      __syncthreads();
    }
    if (tid == 0 && c < C_DIM) atomicAdd(&stats[64 + c], red[0]);
    __syncthreads();
  }
}

// ---------------- fold bn1 into conv weights: cwf[c][0..8]=w*sc, cwf[c][9]=tc ----------------
__global__ __launch_bounds__(64) void bn1_fold_kernel(const float* __restrict__ conv_w,
                                                      const float* __restrict__ conv_b,
                                                      const float* __restrict__ g1,
                                                      const float* __restrict__ b1,
                                                      const float* __restrict__ stats,
                                                      float* __restrict__ cwf) {
  const int c = threadIdx.x;
  if (c >= C_DIM) return;
  const float invN = 1.0f / 4194304.0f;
  float mean = stats[8 + c] * invN;
  float var  = stats[64 + c] * invN - mean * mean;
  float sc = g1[c] * rsqrtf(var + EPS);
  float tc = fmaf(sc, conv_b[c], b1[c] - mean * sc);
  #pragma unroll
  for (int t = 0; t < 9; ++t) cwf[c * 10 + t] = conv_w[c * 9 + t] * sc;
  cwf[c * 10 + 9] = tc;
}

// ---------------- fused conv+bn1+relu+fc GEMM (split-K, full-N block): z[8192][512] partials --------
// Block: 512 thr = 8 waves (2m x 4n), wave tile 64x128, block tile 128m x 512n (ALL of N).
// A tile (conv output) is generated ONCE per block and shared by all 4 n-wave-columns via LDS —
// this removes the 4x redundant A-generation of the previous 128x128 grid.
// Grid (64 m-tiles, KSPLIT h-splits) = 512 blocks = exactly 2 blocks/CU (LDS 48KB -> 3 max).
// Each split covers 64 h values (2 k-tiles of 32); partials accumulate into z via atomicAdd.
__global__ __launch_bounds__(512) void fc_gemm_kernel(const unsigned short* __restrict__ xn,
                                                      const unsigned short* __restrict__ fcw,
                                                      const float* __restrict__ cwf,
                                                      float* __restrict__ z) {
  const int tid  = threadIdx.x;
  const int m0   = blockIdx.x * 128;
  const int hs   = blockIdx.y * 64;   // this split's h range: [hs, hs+64)
  const int lane = tid & 63;
  const int wave = tid >> 6;          // 0..7
  const int wm   = (wave >> 2) * 64;  // 2 m-wave rows
  const int wn   = (wave & 3) * 128;  // 4 n-wave cols
  const int l15  = lane & 15;
  const int qd   = lane >> 4;
  const int am   = tid >> 2;          // row 0..127 this thread generates
  const int ah   = (tid & 3) * 8;     // k-base (0,8,16,24) within 32-wide tile

  __shared__ unsigned short xstage[128][3][36];  // bn0-normalized window [h0-1, h0+33); padded for u32 reads
  __shared__ unsigned short albuf[2][128][40];   // A tile, k padded 32->40 (2-way banks)

  f32x4 acc[4][8];
  #pragma unroll
  for (int a = 0; a < 4; ++a)
    #pragma unroll
    for (int b = 0; b < 8; ++b) {
      f32x4 zv = {0.f, 0.f, 0.f, 0.f};
      acc[a][b] = zv;
    }

  const unsigned short* bbase[8];
  #pragma unroll
  for (int tn = 0; tn < 8; ++tn)
    bbase[tn] = fcw + (size_t)(wn + tn * 16 + l15) * KHW + qd * 8;

  float xw[3][10];

  for (int h0 = hs; h0 < hs + 64; h0 += 32) {
    __syncthreads();
    // stage xn window (coalesced-ish)
    for (int idx = tid; idx < 128 * 3 * 34; idx += 512) {
      int m = idx / 102;
      int rem = idx - m * 102;
      int i = rem / 34;
      int x = rem - i * 34;
      int h = h0 - 1 + x;
      unsigned short v = 0;
      if (h >= 0 && h < H_DIM) v = xn[((size_t)(m0 + m) * 3 + i) * H_DIM + h];
      xstage[m][i][x] = v;
    }
    __syncthreads();
    // per-thread register window: outputs k=ah..ah+7 need taps x=ah..ah+9 (10 elems = 5 u32)
    #pragma unroll
    for (int i = 0; i < 3; ++i) {
      const unsigned int* p = (const unsigned int*)&xstage[am][i][ah];
      #pragma unroll
      for (int j = 0; j < 5; ++j) {
        unsigned int u = p[j];
        xw[i][2 * j]     = __uint_as_float(u << 16);
        xw[i][2 * j + 1] = __uint_as_float(u & 0xFFFF0000u);
      }
    }

    auto agen = [&](int c, int bb) {
      float w[9], tc;
      const float* cw = cwf + c * 10;
      #pragma unroll
      for (int t = 0; t < 9; ++t) w[t] = cw[t];
      tc = cw[9];
      unsigned int pk[4];
      #pragma unroll
      for (int kp = 0; kp < 4; ++kp) {
        float vv[2];
        #pragma unroll
        for (int e = 0; e < 2; ++e) {
          int kk = kp * 2 + e;
          float v = tc;
          #pragma unroll
          for (int i = 0; i < 3; ++i) {
            v = fmaf(w[i * 3 + 0], xw[i][kk],     v);
            v = fmaf(w[i * 3 + 1], xw[i][kk + 1], v);
            v = fmaf(w[i * 3 + 2], xw[i][kk + 2], v);
          }
          vv[e] = fmaxf(v, 0.f);
        }
        asm("v_cvt_pk_bf16_f32 %0, %1, %2" : "=v"(pk[kp]) : "v"(vv[0]), "v"(vv[1]));
      }
      *(uint4*)&albuf[bb][am][ah] = make_uint4(pk[0], pk[1], pk[2], pk[3]);
    };

    agen(0, 0);
    bf16x8 bcur[8];
    #pragma unroll
    for (int tn = 0; tn < 8; ++tn)
      bcur[tn] = *(const bf16x8*)(bbase[tn] + h0);
    __syncthreads();

    #pragma unroll 1
    for (int c = 0; c < C_DIM; ++c) {
      bf16x8 af[4];
      #pragma unroll
      for (int tm = 0; tm < 4; ++tm)
        af[tm] = *(const bf16x8*)&albuf[c & 1][wm + tm * 16 + l15][qd * 8];
      #pragma unroll
      for (int tm = 0; tm < 4; ++tm)
        #pragma unroll
        for (int tn = 0; tn < 8; ++tn)
          acc[tm][tn] = __builtin_amdgcn_mfma_f32_16x16x32_bf16(af[tm], bcur[tn], acc[tm][tn], 0, 0, 0);
      if (c + 1 < C_DIM) {
        bf16x8 bnew[8];
        #pragma unroll
        for (int tn = 0; tn < 8; ++tn)
          bnew[tn] = *(const bf16x8*)(bbase[tn] + (c + 1) * H_DIM + h0);
        agen(c + 1, (c + 1) & 1);
        __syncthreads();
        #pragma unroll
        for (int tn = 0; tn < 8; ++tn) bcur[tn] = bnew[tn];
      } else {
        __syncthreads();
      }
    }
  }

  #pragma unroll
  for (int tm = 0; tm < 4; ++tm)
    #pragma unroll
    for (int tn = 0; tn < 8; ++tn) {
      int col = wn + tn * 16 + l15;
      #pragma unroll
      for (int r = 0; r < 4; ++r) {
        int row = m0 + wm + tm * 16 + qd * 4 + r;
        atomicAdd(&z[(size_t)row * H_DIM + col], acc[tm][tn][r]);
      }
    }
}

// ---------------- bn2 stats: per-column (512) sum & sumsq over B ----------------
__global__ __launch_bounds__(256) void bn2_stats_kernel(const float* __restrict__ z,
                                                        float* __restrict__ stats) {
  const int tid = threadIdx.x;
  const int col = blockIdx.y * 64 + (tid & 63);
  float s = 0.f, qq = 0.f;
  for (int r = blockIdx.x * 4 + (tid >> 6); r < B_SZ; r += gridDim.x * 4) {
    float v = z[(size_t)r * H_DIM + col];
    s += v; qq += v * v;
  }
  __shared__ float ls[256], lq[256];
  ls[tid] = s; lq[tid] = qq;
  __syncthreads();
  if (tid < 64) {
    s  = ls[tid] + ls[tid + 64] + ls[tid + 128] + ls[tid + 192];
    qq = lq[tid] + lq[tid + 64] + lq[tid + 128] + lq[tid + 192];
    atomicAdd(&stats[128 + col], s);
    atomicAdd(&stats[640 + col], qq);
  }
}

// ---------------- zr = bf16(relu(bn2(z))) ----------------
__global__ __launch_bounds__(256) void zr_kernel(const float* __restrict__ z,
                                                 const float* __restrict__ stats,
                                                 const float* __restrict__ g2,
                                                 const float* __restrict__ b2,
                                                 unsigned short* __restrict__ zrb) {
  const float invB = 1.0f / 8192.0f;
  const int stride = gridDim.x * 256;
  for (int i = blockIdx.x * 256 + threadIdx.x; i < B_SZ * H_DIM; i += stride) {
    int col = i & 511;
    float mean = stats[128 + col] * invB;
    float var  = stats[640 + col] * invB - mean * mean;
    float sc = g2[col] * rsqrtf(var + EPS);
    float tc = b2[col] - mean * sc;
    float v = fmaf(z[i], sc, tc);
    zrb[i] = f2bf(fmaxf(v, 0.f));
  }
}

// ---------------- score GEMM: out[8192][20000] = zr @ ent^T, + per-block (max,sumexp) partials ----
__global__ __launch_bounds__(256) void score_gemm_kernel(const unsigned short* __restrict__ zrb,
                                                         const unsigned short* __restrict__ entb,
                                                         float* __restrict__ out,
                                                         float* __restrict__ pm,
                                                         float* __restrict__ ps) {
  const int tid  = threadIdx.x;
  const int m0   = blockIdx.x * 128;
  const int n0   = blockIdx.y * 128;
  const int lane = tid & 63;
  const int wave = tid >> 6;
  const int wm   = (wave >> 1) * 64;
  const int wn   = (wave & 1) * 64;
  const int l15  = lane & 15;
  const int qd   = lane >> 4;

  f32x4 acc[4][4];
  #pragma unroll
  for (int a = 0; a < 4; ++a)
    #pragma unroll
    for (int b = 0; b < 4; ++b) {
      f32x4 zv = {0.f, 0.f, 0.f, 0.f};
      acc[a][b] = zv;
    }

  const unsigned short* ap[4];
  const unsigned short* bp[4];
  #pragma unroll
  for (int t = 0; t < 4; ++t) {
    ap[t] = zrb + (size_t)(m0 + wm + t * 16 + l15) * H_DIM + qd * 8;
    int e = n0 + wn + t * 16 + l15;
    if (e >= NUM_E) e = NUM_E - 1;
    bp[t] = entb + (size_t)e * H_DIM + qd * 8;
  }
  #pragma unroll 2
  for (int k0 = 0; k0 < H_DIM; k0 += 32) {
    bf16x8 af[4], bf[4];
    #pragma unroll
    for (int t = 0; t < 4; ++t) {
      af[t] = *(const bf16x8*)(ap[t] + k0);
      bf[t] = *(const bf16x8*)(bp[t] + k0);
    }
    #pragma unroll
    for (int tm = 0; tm < 4; ++tm)
      #pragma unroll
      for (int tn = 0; tn < 4; ++tn)
        acc[tm][tn] = __builtin_amdgcn_mfma_f32_16x16x32_bf16(af[tm], bf[tn], acc[tm][tn], 0, 0, 0);
  }
  #pragma unroll
  for (int tm = 0; tm < 4; ++tm)
    #pragma unroll
    for (int tn = 0; tn < 4; ++tn) {
      int col = n0 + wn + tn * 16 + l15;
      if (col < NUM_E) {
        #pragma unroll
        for (int r = 0; r < 4; ++r) {
          int row = m0 + wm + tm * 16 + qd * 4 + r;
          out[(size_t)row * NUM_E + col] = acc[tm][tn][r];
        }
      }
    }

  // ---- per-row partial (max, sumexp) over this block's 128 cols ----
  __shared__ float smx[2][2][4][4][4]; // [wmb][wnb][tm][qd][r]
  __shared__ float ssx[2][2][4][4][4];
  const int wmb = wave >> 1, wnb = wave & 1;
  #pragma unroll
  for (int tm = 0; tm < 4; ++tm) {
    #pragma unroll
    for (int r = 0; r < 4; ++r) {
      float m = -3.0e38f;
      #pragma unroll
      for (int tn = 0; tn < 4; ++tn) {
        int col = n0 + wn + tn * 16 + l15;
        if (col < NUM_E) m = fmaxf(m, acc[tm][tn][r]);
      }
      float s = 0.f;
      #pragma unroll
      for (int tn = 0; tn < 4; ++tn) {
        int col = n0 + wn + tn * 16 + l15;
        if (col < NUM_E) s += __expf(acc[tm][tn][r] - m);
      }
      #pragma unroll
      for (int d = 1; d < 16; d <<= 1) {
        float m2 = __shfl_xor(m, d, 64);
        float s2 = __shfl_xor(s, d, 64);
        float Mn = fmaxf(m, m2);
        s = s * __expf(m - Mn) + s2 * __expf(m2 - Mn);
        m = Mn;
      }
      if (l15 == 0) { smx[wmb][wnb][tm][qd][r] = m; ssx[wmb][wnb][tm][qd][r] = s; }
    }
  }
  __syncthreads();
  if (tid < 128) {
    int wmb2 = tid >> 6, rl = tid & 63;
    int tm = rl >> 4, qd2 = (rl >> 2) & 3, r = rl & 3;
    float m1 = smx[wmb2][0][tm][qd2][r], s1 = ssx[wmb2][0][tm][qd2][r];
    float m2 = smx[wmb2][1][tm][qd2][r], s2 = ssx[wmb2][1][tm][qd2][r];
    float Mn = fmaxf(m1, m2);
    float S  = s1 * __expf(m1 - Mn) + s2 * __expf(m2 - Mn);
    int row  = m0 + wmb2 * 64 + rl;
    pm[(size_t)blockIdx.y * B_SZ + row] = Mn;
    ps[(size_t)blockIdx.y * B_SZ + row] = S;
  }
}

// ---------------- combine per-block partials -> lse[row] ----------------
__global__ __launch_bounds__(256) void lse_reduce_kernel(const float* __restrict__ pm,
                                                         const float* __restrict__ ps,
                                                         float* __restrict__ lse) {
  int row = blockIdx.x * 256 + threadIdx.x;  // 8192 rows
  float M = -3.0e38f, S = 0.f;
  for (int nb = 0; nb < NBLK; ++nb) {
    float m2 = pm[(size_t)nb * B_SZ + row];
    float s2 = ps[(size_t)nb * B_SZ + row];
    float Mn = fmaxf(M, m2);
    S = S * __expf(M - Mn) + s2 * __expf(m2 - Mn);
    M = Mn;
  }
  lse[row] = M + __logf(S);
}

// ---------------- streaming subtract: out[row][c] -= lse[row] ----------------
__global__ __launch_bounds__(256) void lsub_kernel(float* __restrict__ out,
                                                   const float* __restrict__ lse) {
  const int row = blockIdx.y;
  const float l = lse[row];
  float4* p = (float4*)(out + (size_t)row * NUM_E);
  int i = blockIdx.x * 256 + threadIdx.x;
  if (i < NUM_E / 4) {
    float4 v = p[i];
    v.x -= l; v.y -= l; v.z -= l; v.w -= l;
    p[i] = v;
  }
}

extern "C" void kernel_launch(void* const* d_in, const int* in_sizes, int n_in,
                              void* d_out, int out_size, void* d_ws, size_t ws_size,
                              hipStream_t stream) {
  const int*   facts  = (const int*)d_in[0];
  const float* ent    = (const float*)d_in[1];
  const float* rel    = (const float*)d_in[2];
  const float* erb    = (const float*)d_in[3];
  const float* conv_w = (const float*)d_in[4];
  const float* conv_b = (const float*)d_in[5];
  const float* fc_w   = (const float*)d_in[6];
  // d_in[7] = fc_b: unused — zeros, and a per-column bias cancels exactly in bn2.
  const float* g0     = (const float*)d_in[8];
  const float* b0     = (const float*)d_in[9];
  const float* g1     = (const float*)d_in[10];
  const float* b1     = (const float*)d_in[11];
  const float* g2     = (const float*)d_in[12];
  const float* b2     = (const float*)d_in[13];

  char* ws = (char*)d_ws;
  // ws layout (total ~97 MB):
  float*          stats = (float*)ws;                          // 16384 B (zeroed); cwf at +8192
  float*          cwf   = (float*)(ws + 8192);                 // 2000 B (50 x 10 folded conv/bn1)
  unsigned short* xn    = (unsigned short*)(ws + 16384);       // 25,165,824 B
  unsigned short* fcw   = (unsigned short*)(ws + 25182208);    // 26,214,400 B
  unsigned short* entb  = (unsigned short*)(ws + 51396608);    // 20,480,000 B
  float*          z     = (float*)(ws + 71876608);             // 16,777,216 B (zeroed; split-K atomics)
  unsigned short* zrb   = (unsigned short*)(ws + 88653824);    //  8,388,608 B
  // z is dead after zr_kernel -> reuse its buffer for softmax partials:
  float*          pm    = (float*)(ws + 71876608);             // 157*8192*4 = 5,144,576 B
  float*          psx   = (float*)(ws + 71876608 + 5144576);   // 5,144,576 B
  float*          lse   = (float*)(ws + 71876608 + 10289152);  // 32,768 B
  float* out = (float*)d_out;

  hipMemsetAsync(stats, 0, 16384, stream);
  hipMemsetAsync(z, 0, 16777216, stream);
  cvt_bf16_kernel<<<2048, 256, 0, stream>>>(ent, entb, (NUM_E * H_DIM) / 4);
  cvt_bf16_kernel<<<2048, 256, 0, stream>>>(fc_w, fcw, (H_DIM * KHW) / 4);
  bn0_stats_kernel<<<1024, 256, 0, stream>>>(facts, ent, rel, erb, stats);
  xn_kernel<<<1024, 256, 0, stream>>>(facts, ent, rel, erb, g0, b0, stats, xn);
  conv_stats_kernel<<<dim3(512, 7), 256, 0, stream>>>(xn, conv_w, conv_b, stats);
  bn1_fold_kernel<<<1, 64, 0, stream>>>(conv_w, conv_b, g1, b1, stats, cwf);
  fc_gemm_kernel<<<dim3(64, KSPLIT), 512, 0, stream>>>(xn, fcw, cwf, z);
  bn2_stats_kernel<<<dim3(64, 8), 256, 0, stream>>>(z, stats);
  zr_kernel<<<2048, 256, 0, stream>>>(z, stats, g2, b2, zrb);
  score_gemm_kernel<<<dim3(64, NBLK), 256, 0, stream>>>(zrb, entb, out, pm, psx);
  lse_reduce_kernel<<<32, 256, 0, stream>>>(pm, psx, lse);
  lsub_kernel<<<dim3(20, 8192), 256, 0, stream>>>(out, lse);
}

// Round 4
// 2235.956 us; speedup vs baseline: 1.4008x; 1.1299x over previous
//
#include <hip/hip_runtime.h>

#define B_SZ   8192
#define NUM_E  20000
#define H_DIM  512
#define C_DIM  50
#define KHW    25600   // C_DIM * H_DIM
#define EPS    1e-5f
#define KSPLIT 8       // fc_gemm split-K factor: each split covers 512/8 = 64 h values
#define NBLK   157     // score n-blocks (157*128 >= 20000)

typedef short bf16x8 __attribute__((ext_vector_type(8)));
typedef float f32x4  __attribute__((ext_vector_type(4)));

__device__ __forceinline__ float bf2f(unsigned short u) {
  return __uint_as_float(((unsigned int)u) << 16);
}
__device__ __forceinline__ unsigned short f2bf(float f) {
  unsigned int u = __float_as_uint(f);
  return (unsigned short)((u + 0x7FFFu + ((u >> 16) & 1u)) >> 16);
}

// ---------------- f32 -> bf16 bulk convert ----------------
__global__ __launch_bounds__(256) void cvt_bf16_kernel(const float* __restrict__ in,
                                                       unsigned short* __restrict__ out,
                                                       int n4) {
  int i = blockIdx.x * 256 + threadIdx.x;
  int stride = gridDim.x * 256;
  for (; i < n4; i += stride) {
    float4 v = reinterpret_cast<const float4*>(in)[i];
    ushort4 o;
    o.x = f2bf(v.x); o.y = f2bf(v.y); o.z = f2bf(v.z); o.w = f2bf(v.w);
    reinterpret_cast<ushort4*>(out)[i] = o;
  }
}

// ---------------- bn0 stats: per-channel (3) sum & sumsq over B*H ----------------
__global__ __launch_bounds__(256) void bn0_stats_kernel(const int* __restrict__ facts,
                                                        const float* __restrict__ ent,
                                                        const float* __restrict__ rel,
                                                        const float* __restrict__ bias,
                                                        float* __restrict__ stats) {
  const int tid = threadIdx.x;
  float s0=0.f,s1=0.f,s2=0.f,q0=0.f,q1=0.f,q2=0.f;
  const int stride = gridDim.x * 256;
  for (int i = blockIdx.x * 256 + tid; i < B_SZ * H_DIM; i += stride) {
    int b = i >> 9, h = i & 511;
    int f0 = facts[b * 3 + 0], f1 = facts[b * 3 + 1];
    float v0 = ent[f0 * H_DIM + h];
    float v1 = rel[f1 * H_DIM + h];
    float v2 = bias[f0 * H_DIM + h];
    s0 += v0; q0 += v0 * v0;
    s1 += v1; q1 += v1 * v1;
    s2 += v2; q2 += v2 * v2;
  }
  __shared__ float red[256];
  float vals[6] = {s0, s1, s2, q0, q1, q2};
  for (int j = 0; j < 6; ++j) {
    red[tid] = vals[j]; __syncthreads();
    for (int off = 128; off > 0; off >>= 1) {
      if (tid < off) red[tid] += red[tid + off];
      __syncthreads();
    }
    if (tid == 0) atomicAdd(&stats[j], red[0]);
    __syncthreads();
  }
}

// ---------------- xn = bn0(gathered x), stored bf16 [B][3][H] ----------------
__global__ __launch_bounds__(256) void xn_kernel(const int* __restrict__ facts,
                                                 const float* __restrict__ ent,
                                                 const float* __restrict__ rel,
                                                 const float* __restrict__ bias,
                                                 const float* __restrict__ g0,
                                                 const float* __restrict__ b0,
                                                 const float* __restrict__ stats,
                                                 unsigned short* __restrict__ xn) {
  const float invN = 1.0f / 4194304.0f;
  float a[3], c[3];
  #pragma unroll
  for (int ch = 0; ch < 3; ++ch) {
    float mean = stats[ch] * invN;
    float var  = stats[3 + ch] * invN - mean * mean;
    float sc = g0[ch] * rsqrtf(var + EPS);
    a[ch] = sc;
    c[ch] = b0[ch] - mean * sc;
  }
  const int stride = gridDim.x * 256;
  for (int i = blockIdx.x * 256 + threadIdx.x; i < B_SZ * H_DIM; i += stride) {
    int b = i >> 9, h = i & 511;
    int f0 = facts[b * 3 + 0], f1 = facts[b * 3 + 1];
    xn[(b * 3 + 0) * H_DIM + h] = f2bf(fmaf(ent[f0 * H_DIM + h],  a[0], c[0]));
    xn[(b * 3 + 1) * H_DIM + h] = f2bf(fmaf(rel[f1 * H_DIM + h],  a[1], c[1]));
    xn[(b * 3 + 2) * H_DIM + h] = f2bf(fmaf(bias[f0 * H_DIM + h], a[2], c[2]));
  }
}

// ---------------- conv output stats (pre-bn1): per-C sum & sumsq over B*H ----------------
__global__ __launch_bounds__(256) void conv_stats_kernel(const unsigned short* __restrict__ xn,
                                                         const float* __restrict__ conv_w,
                                                         const float* __restrict__ conv_b,
                                                         float* __restrict__ stats) {
  const int tid = threadIdx.x;
  const int cg = blockIdx.y;   // 7 groups of 8 channels
  float w[8][9], cb[8];
  #pragma unroll
  for (int j = 0; j < 8; ++j) {
    int c = cg * 8 + j;
    if (c < C_DIM) {
      #pragma unroll
      for (int t = 0; t < 9; ++t) w[j][t] = conv_w[c * 9 + t];
      cb[j] = conv_b[c];
    } else {
      #pragma unroll
      for (int t = 0; t < 9; ++t) w[j][t] = 0.f;
      cb[j] = 0.f;
    }
  }
  float s[8], qv[8];
  #pragma unroll
  for (int j = 0; j < 8; ++j) { s[j] = 0.f; qv[j] = 0.f; }
  const int stride = gridDim.x * 256;
  for (int i = blockIdx.x * 256 + tid; i < B_SZ * H_DIM; i += stride) {
    int b = i >> 9, h = i & 511;
    float xv[9];
    #pragma unroll
    for (int ii = 0; ii < 3; ++ii) {
      const unsigned short* row = xn + ((size_t)b * 3 + ii) * H_DIM;
      xv[ii * 3 + 0] = (h > 0)   ? bf2f(row[h - 1]) : 0.f;
      xv[ii * 3 + 1] = bf2f(row[h]);
      xv[ii * 3 + 2] = (h < 511) ? bf2f(row[h + 1]) : 0.f;
    }
    #pragma unroll
    for (int j = 0; j < 8; ++j) {
      float v = cb[j];
      #pragma unroll
      for (int t = 0; t < 9; ++t) v = fmaf(w[j][t], xv[t], v);
      s[j] += v; qv[j] += v * v;
    }
  }
  __shared__ float red[256];
  #pragma unroll 1
  for (int j = 0; j < 8; ++j) {
    int c = cg * 8 + j;
    red[tid] = s[j]; __syncthreads();
    for (int off = 128; off > 0; off >>= 1) {
      if (tid < off) red[tid] += red[tid + off];
      __syncthreads();
    }
    if (tid == 0 && c < C_DIM) atomicAdd(&stats[8 + c], red[0]);
    __syncthreads();
    red[tid] = qv[j]; __syncthreads();
    for (int off = 128; off > 0; off >>= 1) {
      if (tid < off) red[tid] += red[tid + off];
      __syncthreads();
    }
    if (tid == 0 && c < C_DIM) atomicAdd(&stats[64 + c], red[0]);
    __syncthreads();
  }
}

// ---------------- fold bn1 into conv weights: cwf[c][0..8]=w*sc, cwf[c][9]=tc ----------------
__global__ __launch_bounds__(64) void bn1_fold_kernel(const float* __restrict__ conv_w,
                                                      const float* __restrict__ conv_b,
                                                      const float* __restrict__ g1,
                                                      const float* __restrict__ b1,
                                                      const float* __restrict__ stats,
                                                      float* __restrict__ cwf) {
  const int c = threadIdx.x;
  if (c >= C_DIM) return;
  const float invN = 1.0f / 4194304.0f;
  float mean = stats[8 + c] * invN;
  float var  = stats[64 + c] * invN - mean * mean;
  float sc = g1[c] * rsqrtf(var + EPS);
  float tc = fmaf(sc, conv_b[c], b1[c] - mean * sc);
  #pragma unroll
  for (int t = 0; t < 9; ++t) cwf[c * 10 + t] = conv_w[c * 9 + t] * sc;
  cwf[c * 10 + 9] = tc;
}

// ---------------- fused conv+bn1+relu+fc GEMM (split-K, full-N block): z[8192][512] partials --------
__global__ __launch_bounds__(512) void fc_gemm_kernel(const unsigned short* __restrict__ xn,
                                                      const unsigned short* __restrict__ fcw,
                                                      const float* __restrict__ cwf,
                                                      float* __restrict__ z) {
  const int tid  = threadIdx.x;
  const int m0   = blockIdx.x * 128;
  const int hs   = blockIdx.y * 64;   // this split's h range: [hs, hs+64)
  const int lane = tid & 63;
  const int wave = tid >> 6;          // 0..7
  const int wm   = (wave >> 2) * 64;  // 2 m-wave rows
  const int wn   = (wave & 3) * 128;  // 4 n-wave cols
  const int l15  = lane & 15;
  const int qd   = lane >> 4;
  const int am   = tid >> 2;          // row 0..127 this thread generates
  const int ah   = (tid & 3) * 8;     // k-base (0,8,16,24) within 32-wide tile

  __shared__ unsigned short xstage[128][3][36];  // bn0-normalized window [h0-1, h0+33); padded for u32 reads
  __shared__ unsigned short albuf[2][128][40];   // A tile, k padded 32->40 (2-way banks)

  f32x4 acc[4][8];
  #pragma unroll
  for (int a = 0; a < 4; ++a)
    #pragma unroll
    for (int b = 0; b < 8; ++b) {
      f32x4 zv = {0.f, 0.f, 0.f, 0.f};
      acc[a][b] = zv;
    }

  const unsigned short* bbase[8];
  #pragma unroll
  for (int tn = 0; tn < 8; ++tn)
    bbase[tn] = fcw + (size_t)(wn + tn * 16 + l15) * KHW + qd * 8;

  float xw[3][10];

  for (int h0 = hs; h0 < hs + 64; h0 += 32) {
    __syncthreads();
    // stage xn window (coalesced-ish)
    for (int idx = tid; idx < 128 * 3 * 34; idx += 512) {
      int m = idx / 102;
      int rem = idx - m * 102;
      int i = rem / 34;
      int x = rem - i * 34;
      int h = h0 - 1 + x;
      unsigned short v = 0;
      if (h >= 0 && h < H_DIM) v = xn[((size_t)(m0 + m) * 3 + i) * H_DIM + h];
      xstage[m][i][x] = v;
    }
    __syncthreads();
    // per-thread register window: outputs k=ah..ah+7 need taps x=ah..ah+9 (10 elems = 5 u32)
    #pragma unroll
    for (int i = 0; i < 3; ++i) {
      const unsigned int* p = (const unsigned int*)&xstage[am][i][ah];
      #pragma unroll
      for (int j = 0; j < 5; ++j) {
        unsigned int u = p[j];
        xw[i][2 * j]     = __uint_as_float(u << 16);
        xw[i][2 * j + 1] = __uint_as_float(u & 0xFFFF0000u);
      }
    }

    auto agen = [&](int c, int bb) {
      float w[9], tc;
      const float* cw = cwf + c * 10;
      #pragma unroll
      for (int t = 0; t < 9; ++t) w[t] = cw[t];
      tc = cw[9];
      unsigned int pk[4];
      #pragma unroll
      for (int kp = 0; kp < 4; ++kp) {
        float vv[2];
        #pragma unroll
        for (int e = 0; e < 2; ++e) {
          int kk = kp * 2 + e;
          float v = tc;
          #pragma unroll
          for (int i = 0; i < 3; ++i) {
            v = fmaf(w[i * 3 + 0], xw[i][kk],     v);
            v = fmaf(w[i * 3 + 1], xw[i][kk + 1], v);
            v = fmaf(w[i * 3 + 2], xw[i][kk + 2], v);
          }
          vv[e] = fmaxf(v, 0.f);
        }
        asm("v_cvt_pk_bf16_f32 %0, %1, %2" : "=v"(pk[kp]) : "v"(vv[0]), "v"(vv[1]));
      }
      *(uint4*)&albuf[bb][am][ah] = make_uint4(pk[0], pk[1], pk[2], pk[3]);
    };

    agen(0, 0);
    bf16x8 bcur[8];
    #pragma unroll
    for (int tn = 0; tn < 8; ++tn)
      bcur[tn] = *(const bf16x8*)(bbase[tn] + h0);
    __syncthreads();

    #pragma unroll 1
    for (int c = 0; c < C_DIM; ++c) {
      bf16x8 af[4];
      #pragma unroll
      for (int tm = 0; tm < 4; ++tm)
        af[tm] = *(const bf16x8*)&albuf[c & 1][wm + tm * 16 + l15][qd * 8];
      #pragma unroll
      for (int tm = 0; tm < 4; ++tm)
        #pragma unroll
        for (int tn = 0; tn < 8; ++tn)
          acc[tm][tn] = __builtin_amdgcn_mfma_f32_16x16x32_bf16(af[tm], bcur[tn], acc[tm][tn], 0, 0, 0);
      if (c + 1 < C_DIM) {
        bf16x8 bnew[8];
        #pragma unroll
        for (int tn = 0; tn < 8; ++tn)
          bnew[tn] = *(const bf16x8*)(bbase[tn] + (c + 1) * H_DIM + h0);
        agen(c + 1, (c + 1) & 1);
        __syncthreads();
        #pragma unroll
        for (int tn = 0; tn < 8; ++tn) bcur[tn] = bnew[tn];
      } else {
        __syncthreads();
      }
    }
  }

  #pragma unroll
  for (int tm = 0; tm < 4; ++tm)
    #pragma unroll
    for (int tn = 0; tn < 8; ++tn) {
      int col = wn + tn * 16 + l15;
      #pragma unroll
      for (int r = 0; r < 4; ++r) {
        int row = m0 + wm + tm * 16 + qd * 4 + r;
        atomicAdd(&z[(size_t)row * H_DIM + col], acc[tm][tn][r]);
      }
    }
}

// ---------------- bn2 stats: per-column (512) sum & sumsq over B ----------------
__global__ __launch_bounds__(256) void bn2_stats_kernel(const float* __restrict__ z,
                                                        float* __restrict__ stats) {
  const int tid = threadIdx.x;
  const int col = blockIdx.y * 64 + (tid & 63);
  float s = 0.f, qq = 0.f;
  for (int r = blockIdx.x * 4 + (tid >> 6); r < B_SZ; r += gridDim.x * 4) {
    float v = z[(size_t)r * H_DIM + col];
    s += v; qq += v * v;
  }
  __shared__ float ls[256], lq[256];
  ls[tid] = s; lq[tid] = qq;
  __syncthreads();
  if (tid < 64) {
    s  = ls[tid] + ls[tid + 64] + ls[tid + 128] + ls[tid + 192];
    qq = lq[tid] + lq[tid + 64] + lq[tid + 128] + lq[tid + 192];
    atomicAdd(&stats[128 + col], s);
    atomicAdd(&stats[640 + col], qq);
  }
}

// ---------------- zr = bf16(relu(bn2(z))) ----------------
__global__ __launch_bounds__(256) void zr_kernel(const float* __restrict__ z,
                                                 const float* __restrict__ stats,
                                                 const float* __restrict__ g2,
                                                 const float* __restrict__ b2,
                                                 unsigned short* __restrict__ zrb) {
  const float invB = 1.0f / 8192.0f;
  const int stride = gridDim.x * 256;
  for (int i = blockIdx.x * 256 + threadIdx.x; i < B_SZ * H_DIM; i += stride) {
    int col = i & 511;
    float mean = stats[128 + col] * invB;
    float var  = stats[640 + col] * invB - mean * mean;
    float sc = g2[col] * rsqrtf(var + EPS);
    float tc = b2[col] - mean * sc;
    float v = fmaf(z[i], sc, tc);
    zrb[i] = f2bf(fmaxf(v, 0.f));
  }
}

// ---------------- score GEMM: out[8192][20000] = zr @ ent^T, LDS-staged (m97 structure) ----------
// 128x128 tile, BK=64, double-buffered LDS via global_load_lds (width 16), counted vmcnt(8),
// raw s_barrier. T2 XOR-swizzle (col16 ^= row&7) applied on the GLOBAL source address
// (global_load_lds writes linearly) and on the ds_read side — involution, rule #21.
// Fused per-block softmax partials (max, sumexp) -> pm/ps.
__global__ __launch_bounds__(256) void score_gemm_kernel(const unsigned short* __restrict__ zrb,
                                                         const unsigned short* __restrict__ entb,
                                                         float* __restrict__ out,
                                                         float* __restrict__ pm,
                                                         float* __restrict__ ps) {
  const int tid  = threadIdx.x;
  const int m0   = blockIdx.x * 128;
  const int n0   = blockIdx.y * 128;
  const int lane = tid & 63;
  const int wave = tid >> 6;
  const int wm   = (wave >> 1) * 64;
  const int wn   = (wave & 1) * 64;
  const int l15  = lane & 15;
  const int qd   = lane >> 4;

  __shared__ unsigned short As[2][128 * 64];
  __shared__ unsigned short Bs[2][128 * 64];

  f32x4 acc[4][4];
  #pragma unroll
  for (int a = 0; a < 4; ++a)
    #pragma unroll
    for (int b = 0; b < 4; ++b) {
      f32x4 zv = {0.f, 0.f, 0.f, 0.f};
      acc[a][b] = zv;
    }

  // stage one 128x64 bf16 tile: 4 calls/wave, each call = 8 rows (64 lanes x 16B).
  // LDS dest is linear (row*128B + (lane&7)*16B); global src col is pre-swizzled.
  auto stage = [&](const unsigned short* __restrict__ src, int row0, int maxrow,
                   unsigned short* dst, int k0) {
    #pragma unroll
    for (int i = 0; i < 4; ++i) {
      int rgrp = i * 32 + wave * 8;
      int row  = rgrp + (lane >> 3);
      int srow = row0 + row;
      if (srow > maxrow) srow = maxrow;       // entb tail clamp (cols >= NUM_E discarded later)
      int cs = (lane & 7) ^ (row & 7);        // swizzled source 16B-chunk
      const unsigned short* g = src + (size_t)srow * H_DIM + k0 + cs * 8;
      __builtin_amdgcn_global_load_lds(
          (const __attribute__((address_space(1))) void*)g,
          (__attribute__((address_space(3))) void*)(dst + rgrp * 64),
          16, 0, 0);
    }
  };

  // prologue: tile 0 into buffer 0
  stage(zrb,  m0, B_SZ  - 1, As[0], 0);
  stage(entb, n0, NUM_E - 1, Bs[0], 0);

  #pragma unroll 1
  for (int t = 0; t < 8; ++t) {
    const int cur = t & 1;
    if (t < 7) {
      // issue next tile's 8 loads/wave, then wait only for current tile's 8 (counted vmcnt)
      stage(zrb,  m0, B_SZ  - 1, As[cur ^ 1], (t + 1) * 64);
      stage(entb, n0, NUM_E - 1, Bs[cur ^ 1], (t + 1) * 64);
      asm volatile("s_waitcnt vmcnt(8)" ::: "memory");
    } else {
      asm volatile("s_waitcnt vmcnt(0)" ::: "memory");
    }
    __builtin_amdgcn_s_barrier();
    __builtin_amdgcn_sched_barrier(0);

    const unsigned short* At = As[cur];
    const unsigned short* Bt = Bs[cur];
    #pragma unroll
    for (int ks = 0; ks < 2; ++ks) {
      bf16x8 af[4], bfr[4];
      #pragma unroll
      for (int f = 0; f < 4; ++f) {
        int ra = wm + f * 16 + l15;
        af[f]  = *(const bf16x8*)&At[ra * 64 + (((ks * 4 + qd) ^ (ra & 7)) << 3)];
        int rb = wn + f * 16 + l15;
        bfr[f] = *(const bf16x8*)&Bt[rb * 64 + (((ks * 4 + qd) ^ (rb & 7)) << 3)];
      }
      #pragma unroll
      for (int tm = 0; tm < 4; ++tm)
        #pragma unroll
        for (int tn = 0; tn < 4; ++tn)
          acc[tm][tn] = __builtin_amdgcn_mfma_f32_16x16x32_bf16(af[tm], bfr[tn], acc[tm][tn], 0, 0, 0);
    }
    __builtin_amdgcn_sched_barrier(0);
    __builtin_amdgcn_s_barrier();   // all waves done reading buf[cur] before it's restaged
  }

  #pragma unroll
  for (int tm = 0; tm < 4; ++tm)
    #pragma unroll
    for (int tn = 0; tn < 4; ++tn) {
      int col = n0 + wn + tn * 16 + l15;
      if (col < NUM_E) {
        #pragma unroll
        for (int r = 0; r < 4; ++r) {
          int row = m0 + wm + tm * 16 + qd * 4 + r;
          out[(size_t)row * NUM_E + col] = acc[tm][tn][r];
        }
      }
    }

  // ---- per-row partial (max, sumexp) over this block's 128 cols ----
  __shared__ float smx[2][2][4][4][4]; // [wmb][wnb][tm][qd][r]
  __shared__ float ssx[2][2][4][4][4];
  const int wmb = wave >> 1, wnb = wave & 1;
  #pragma unroll
  for (int tm = 0; tm < 4; ++tm) {
    #pragma unroll
    for (int r = 0; r < 4; ++r) {
      float m = -3.0e38f;
      #pragma unroll
      for (int tn = 0; tn < 4; ++tn) {
        int col = n0 + wn + tn * 16 + l15;
        if (col < NUM_E) m = fmaxf(m, acc[tm][tn][r]);
      }
      float s = 0.f;
      #pragma unroll
      for (int tn = 0; tn < 4; ++tn) {
        int col = n0 + wn + tn * 16 + l15;
        if (col < NUM_E) s += __expf(acc[tm][tn][r] - m);
      }
      #pragma unroll
      for (int d = 1; d < 16; d <<= 1) {
        float m2 = __shfl_xor(m, d, 64);
        float s2 = __shfl_xor(s, d, 64);
        float Mn = fmaxf(m, m2);
        s = s * __expf(m - Mn) + s2 * __expf(m2 - Mn);
        m = Mn;
      }
      if (l15 == 0) { smx[wmb][wnb][tm][qd][r] = m; ssx[wmb][wnb][tm][qd][r] = s; }
    }
  }
  __syncthreads();
  if (tid < 128) {
    int wmb2 = tid >> 6, rl = tid & 63;
    int tm = rl >> 4, qd2 = (rl >> 2) & 3, r = rl & 3;
    float m1 = smx[wmb2][0][tm][qd2][r], s1 = ssx[wmb2][0][tm][qd2][r];
    float m2 = smx[wmb2][1][tm][qd2][r], s2 = ssx[wmb2][1][tm][qd2][r];
    float Mn = fmaxf(m1, m2);
    float S  = s1 * __expf(m1 - Mn) + s2 * __expf(m2 - Mn);
    int row  = m0 + wmb2 * 64 + rl;
    pm[(size_t)blockIdx.y * B_SZ + row] = Mn;
    ps[(size_t)blockIdx.y * B_SZ + row] = S;
  }
}

// ---------------- combine per-block partials -> lse[row] ----------------
__global__ __launch_bounds__(256) void lse_reduce_kernel(const float* __restrict__ pm,
                                                         const float* __restrict__ ps,
                                                         float* __restrict__ lse) {
  int row = blockIdx.x * 256 + threadIdx.x;  // 8192 rows
  float M = -3.0e38f, S = 0.f;
  for (int nb = 0; nb < NBLK; ++nb) {
    float m2 = pm[(size_t)nb * B_SZ + row];
    float s2 = ps[(size_t)nb * B_SZ + row];
    float Mn = fmaxf(M, m2);
    S = S * __expf(M - Mn) + s2 * __expf(m2 - Mn);
    M = Mn;
  }
  lse[row] = M + __logf(S);
}

// ---------------- streaming subtract: out[row][c] -= lse[row] ----------------
__global__ __launch_bounds__(256) void lsub_kernel(float* __restrict__ out,
                                                   const float* __restrict__ lse) {
  const int row = blockIdx.y;
  const float l = lse[row];
  float4* p = (float4*)(out + (size_t)row * NUM_E);
  int i = blockIdx.x * 256 + threadIdx.x;
  if (i < NUM_E / 4) {
    float4 v = p[i];
    v.x -= l; v.y -= l; v.z -= l; v.w -= l;
    p[i] = v;
  }
}

extern "C" void kernel_launch(void* const* d_in, const int* in_sizes, int n_in,
                              void* d_out, int out_size, void* d_ws, size_t ws_size,
                              hipStream_t stream) {
  const int*   facts  = (const int*)d_in[0];
  const float* ent    = (const float*)d_in[1];
  const float* rel    = (const float*)d_in[2];
  const float* erb    = (const float*)d_in[3];
  const float* conv_w = (const float*)d_in[4];
  const float* conv_b = (const float*)d_in[5];
  const float* fc_w   = (const float*)d_in[6];
  // d_in[7] = fc_b: unused — zeros, and a per-column bias cancels exactly in bn2.
  const float* g0     = (const float*)d_in[8];
  const float* b0     = (const float*)d_in[9];
  const float* g1     = (const float*)d_in[10];
  const float* b1     = (const float*)d_in[11];
  const float* g2     = (const float*)d_in[12];
  const float* b2     = (const float*)d_in[13];

  char* ws = (char*)d_ws;
  // ws layout (total ~97 MB):
  float*          stats = (float*)ws;                          // 16384 B (zeroed); cwf at +8192
  float*          cwf   = (float*)(ws + 8192);                 // 2000 B (50 x 10 folded conv/bn1)
  unsigned short* xn    = (unsigned short*)(ws + 16384);       // 25,165,824 B
  unsigned short* fcw   = (unsigned short*)(ws + 25182208);    // 26,214,400 B
  unsigned short* entb  = (unsigned short*)(ws + 51396608);    // 20,480,000 B
  float*          z     = (float*)(ws + 71876608);             // 16,777,216 B (zeroed; split-K atomics)
  unsigned short* zrb   = (unsigned short*)(ws + 88653824);    //  8,388,608 B
  // z is dead after zr_kernel -> reuse its buffer for softmax partials:
  float*          pm    = (float*)(ws + 71876608);             // 157*8192*4 = 5,144,576 B
  float*          psx   = (float*)(ws + 71876608 + 5144576);   // 5,144,576 B
  float*          lse   = (float*)(ws + 71876608 + 10289152);  // 32,768 B
  float* out = (float*)d_out;

  hipMemsetAsync(stats, 0, 16384, stream);
  hipMemsetAsync(z, 0, 16777216, stream);
  cvt_bf16_kernel<<<2048, 256, 0, stream>>>(ent, entb, (NUM_E * H_DIM) / 4);
  cvt_bf16_kernel<<<2048, 256, 0, stream>>>(fc_w, fcw, (H_DIM * KHW) / 4);
  bn0_stats_kernel<<<1024, 256, 0, stream>>>(facts, ent, rel, erb, stats);
  xn_kernel<<<1024, 256, 0, stream>>>(facts, ent, rel, erb, g0, b0, stats, xn);
  conv_stats_kernel<<<dim3(512, 7), 256, 0, stream>>>(xn, conv_w, conv_b, stats);
  bn1_fold_kernel<<<1, 64, 0, stream>>>(conv_w, conv_b, g1, b1, stats, cwf);
  fc_gemm_kernel<<<dim3(64, KSPLIT), 512, 0, stream>>>(xn, fcw, cwf, z);
  bn2_stats_kernel<<<dim3(64, 8), 256, 0, stream>>>(z, stats);
  zr_kernel<<<2048, 256, 0, stream>>>(z, stats, g2, b2, zrb);
  score_gemm_kernel<<<dim3(64, NBLK), 256, 0, stream>>>(zrb, entb, out, pm, psx);
  lse_reduce_kernel<<<32, 256, 0, stream>>>(pm, psx, lse);
  lsub_kernel<<<dim3(20, 8192), 256, 0, stream>>>(out, lse);
}